// Round 2
// baseline (655.214 us; speedup 1.0000x reference)
//
#include <hip/hip_runtime.h>

// Problem constants (fixed by the reference):
//   x        [B=4096, D=16384] fp32
//   hashProj [D=16384, E=1024] fp32, exactly one nonzero (+-1) per row
//   out      [B=4096, E=1024]  fp32 = x @ hashProj
#define DIM_D 16384
#define DIM_E 1024
#define DIM_B 4096

// ---------------------------------------------------------------------------
// Design: hashProj row j has exactly one nonzero (+-1) at column e = h(j).
// So out[b,e] = sum_{j: h(j)=e} sgn(j) * x[b,j]  -- a 16-bit-indexed scatter.
//
// K1 packs (bucket, sign) per feature into idx16[j] = e | (neg ? 0x8000 : 0)
// (bucket needs 10 bits; 32 KiB total -> L1/L2-resident for every block of K2).
// K2 owns one batch row per block: zero a 1024-float LDS accumulator, stream
// the x row straight from HBM (coalesced float4, no LDS staging), flip the
// fp32 sign bit per entry (exact; +-1 multiply == sign XOR), ds_add_f32 into
// the accumulator, write the row coalesced. DS-pipe cost (~16 atomics/thread,
// random banks ~2x serialization) sits well under the HBM share per row, so
// the kernel is pinned to the x read stream (~44 us for 256 MiB).
//
// vs. the previous ELL design this deletes: the memset dispatch, the fill
// kernel (16K global atomics), ~450 MiB aggregate L2 ELL traffic, the
// wave-max shuffle, and 60 KiB/block of LDS. Workspace = 32 KiB, fully
// rewritten every call (safe under harness re-poison).
// ---------------------------------------------------------------------------

// K1: one wave per hashProj row, coalesced float4 scan of 1024 floats;
// exactly one lane finds the nonzero and writes the packed entry.
__global__ __launch_bounds__(256) void hash_extract(
    const float* __restrict__ hashProj,
    unsigned short* __restrict__ idx16) {
  const int wave = threadIdx.x >> 6;
  const int lane = threadIdx.x & 63;
  const int row = blockIdx.x * 4 + wave;   // 4096 blocks x 4 waves = 16384 rows
  const float4* rp = (const float4*)(hashProj + (size_t)row * DIM_E);
  int found_e = -1;
  float found_s = 0.f;
#pragma unroll
  for (int k = 0; k < 4; ++k) {
    const int p = lane + 64 * k;           // float4 position within row
    float4 v = rp[p];
    const int base = p * 4;
    if (v.x != 0.f) { found_e = base + 0; found_s = v.x; }
    if (v.y != 0.f) { found_e = base + 1; found_s = v.y; }
    if (v.z != 0.f) { found_e = base + 2; found_s = v.z; }
    if (v.w != 0.f) { found_e = base + 3; found_s = v.w; }
  }
  if (found_e >= 0) {
    idx16[row] =
        (unsigned short)(found_e | ((found_s < 0.f) ? 0x8000 : 0));
  }
}

// Apply packed sign bit to x value: exact (+-1 multiply == fp32 sign XOR).
__device__ __forceinline__ float apply_sign(float v, unsigned int u) {
  return __int_as_float(__float_as_int(v) ^ (int)((u & 0x8000u) << 16));
}

// K2: one 1024-thread block per batch row; LDS = 1024-float bucket
// accumulator (4 KiB -> occupancy wave-limited at 2 blocks/CU, 32 waves).
__global__ __launch_bounds__(1024) void hash_scatter(
    const float* __restrict__ x,
    const unsigned short* __restrict__ idx16,
    float* __restrict__ out) {
  __shared__ float acc[DIM_E];
  const int t = threadIdx.x;
  const int b = blockIdx.x;
  acc[t] = 0.f;
  __syncthreads();

  const float4* xp = (const float4*)(x + (size_t)b * DIM_D);
  const ushort4* ip = (const ushort4*)idx16;

  // 16 features per thread: load all 4 (float4, ushort4) pairs up front
  // (x from HBM, idx16 from L1/L2), then issue the 16 LDS atomics.
  float4 xv[4];
  ushort4 uv[4];
#pragma unroll
  for (int i = 0; i < 4; ++i) {
    const int p = t + i * 1024;
    xv[i] = xp[p];
    uv[i] = ip[p];
  }
#pragma unroll
  for (int i = 0; i < 4; ++i) {
    atomicAdd(&acc[uv[i].x & (DIM_E - 1)], apply_sign(xv[i].x, uv[i].x));
    atomicAdd(&acc[uv[i].y & (DIM_E - 1)], apply_sign(xv[i].y, uv[i].y));
    atomicAdd(&acc[uv[i].z & (DIM_E - 1)], apply_sign(xv[i].z, uv[i].z));
    atomicAdd(&acc[uv[i].w & (DIM_E - 1)], apply_sign(xv[i].w, uv[i].w));
  }
  __syncthreads();

  out[(size_t)b * DIM_E + t] = acc[t];
}

extern "C" void kernel_launch(void* const* d_in, const int* in_sizes, int n_in,
                              void* d_out, int out_size, void* d_ws, size_t ws_size,
                              hipStream_t stream) {
  const float* x = (const float*)d_in[0];
  const float* hashProj = (const float*)d_in[1];
  float* out = (float*)d_out;

  unsigned short* idx16 = (unsigned short*)d_ws;  // 32 KiB, fully rewritten

  hash_extract<<<DIM_D / 4, 256, 0, stream>>>(hashProj, idx16);
  hash_scatter<<<DIM_B, 1024, 0, stream>>>(x, idx16, out);
}

// Round 3
// 395.914 us; speedup vs baseline: 1.6549x; 1.6549x over previous
//
#include <hip/hip_runtime.h>

// Problem constants (fixed by the reference):
//   x        [B=4096, D=16384] fp32
//   hashProj [D=16384, E=1024] fp32, exactly one nonzero (+-1) per row
//   out      [B=4096, E=1024]  fp32 = x @ hashProj
#define DIM_D 16384
#define DIM_E 1024
#define DIM_B 4096
#define ELL_CAP 64   // bucket capacity; counts ~Poisson(16), P(>64) ~ 1e-50

// ---------------------------------------------------------------------------
// Architecture (round-1 ELL gather, refined):
//   K1: scan hashProj rows (coalesced float4), founder lane claims a slot in
//       its bucket via atomicAdd(cursor) and writes a USHORT entry
//       (j | neg<<15) into the transposed ELL.
//   K2: one block per batch row: stage x row in LDS (64 KiB -> 2 blocks/CU,
//       stage/compute alternation keeps HBM fed), then thread e walks bucket
//       e with a per-wave uniform group count; entries beyond a bucket's own
//       count are masked to +0.0f in VALU (so the ELL needs NO pad prefill --
//       poisoned garbage entries decode in-range and get zeroed).
// LDS atomics (round 2) measured 3.25 cyc/lane-op serialization -- avoided.
// Workspace: ell 128 KiB (ushort) + cursor 4 KiB; only cursor needs memset.
// ---------------------------------------------------------------------------

__global__ __launch_bounds__(256) void hash_extract_fill(
    const float* __restrict__ hashProj,
    int* __restrict__ cursor,
    unsigned short* __restrict__ ell) {
  const int wave = threadIdx.x >> 6;
  const int lane = threadIdx.x & 63;
  const int row = blockIdx.x * 4 + wave;   // 4096 blocks x 4 waves = 16384 rows
  const float4* rp = (const float4*)(hashProj + (size_t)row * DIM_E);
  int found_e = -1;
  float found_s = 0.f;
#pragma unroll
  for (int k = 0; k < 4; ++k) {
    const int p = lane + 64 * k;           // float4 position within row
    float4 v = rp[p];
    const int base = p * 4;
    if (v.x != 0.f) { found_e = base + 0; found_s = v.x; }
    if (v.y != 0.f) { found_e = base + 1; found_s = v.y; }
    if (v.z != 0.f) { found_e = base + 2; found_s = v.z; }
    if (v.w != 0.f) { found_e = base + 3; found_s = v.w; }
  }
  if (found_e >= 0) {
    const int slot = atomicAdd(&cursor[found_e], 1);   // cursor starts at 0
    if (slot < ELL_CAP) {
      // group g = slot>>2 lives at ushort4 index g*1024+e (lane-consecutive
      // e -> coalesced 8B loads in the gather).
      ell[(slot >> 2) * (4 * DIM_E) + 4 * found_e + (slot & 3)] =
          (unsigned short)(row | ((found_s < 0.f) ? 0x8000 : 0));
    }
  }
}

// Decode entry q (k-th slot of a group whose remaining count is r):
//   valid (k < r): +-xs[j]  (sign bit 15 -> fp32 sign XOR, exact)
//   invalid      : +0.0f    (garbage entries decode in-range, then masked)
__device__ __forceinline__ float ell_val(const float* xs, int q, int k, int r) {
  float v = xs[q & (DIM_D - 1)];
  int iv = __float_as_int(v);
  iv ^= (q & 0x8000) << 16;        // bit15 -> fp32 sign bit
  iv &= (k - r) >> 31;             // k < r ? ~0 : 0
  return __int_as_float(iv);
}

__global__ __launch_bounds__(1024) void hash_gather(
    const float* __restrict__ x,
    const int* __restrict__ cursor,
    const unsigned short* __restrict__ ell,
    float* __restrict__ out) {
  __shared__ float xs[DIM_D];
  const int t = threadIdx.x;
  const int b = blockIdx.x;
  const float4* xp = (const float4*)(x + (size_t)b * DIM_D);
  float4* xs4 = (float4*)xs;
#pragma unroll
  for (int i = 0; i < DIM_D / 4 / 1024; ++i) {   // 4 float4s per thread
    const int p = t + i * 1024;
    xs4[p] = xp[p];
  }
  __syncthreads();

  // Own bucket count (exact) + per-wave uniform group count.
  int c = cursor[t];
  if (c > ELL_CAP) c = ELL_CAP;
  int m = c;
#pragma unroll
  for (int off = 32; off >= 1; off >>= 1)
    m = max(m, __shfl_xor(m, off));
  const int G = (m + 3) >> 2;                    // wave-uniform trip count

  const ushort4* ep = (const ushort4*)ell;
  float s0 = 0.f, s1 = 0.f, s2 = 0.f, s3 = 0.f;
  ushort4 q = ep[t];                             // prefetch group 0
  int r = c;
  for (int g = 1; g < G; ++g) {
    ushort4 qn = ep[g * DIM_E + t];              // prefetch next group
    s0 += ell_val(xs, q.x, 0, r);
    s1 += ell_val(xs, q.y, 1, r);
    s2 += ell_val(xs, q.z, 2, r);
    s3 += ell_val(xs, q.w, 3, r);
    q = qn;
    r = c - g * 4;
  }
  s0 += ell_val(xs, q.x, 0, r);
  s1 += ell_val(xs, q.y, 1, r);
  s2 += ell_val(xs, q.z, 2, r);
  s3 += ell_val(xs, q.w, 3, r);
  out[(size_t)b * DIM_E + t] = (s0 + s1) + (s2 + s3);
}

extern "C" void kernel_launch(void* const* d_in, const int* in_sizes, int n_in,
                              void* d_out, int out_size, void* d_ws, size_t ws_size,
                              hipStream_t stream) {
  const float* x = (const float*)d_in[0];
  const float* hashProj = (const float*)d_in[1];
  float* out = (float*)d_out;

  char* ws = (char*)d_ws;
  unsigned short* ell = (unsigned short*)ws;              // 128 KiB
  int* cursor = (int*)(ws + (size_t)ELL_CAP * DIM_E * 2); // 4 KiB

  hipMemsetAsync(cursor, 0, DIM_E * sizeof(int), stream); // only cursors
  hash_extract_fill<<<DIM_D / 4, 256, 0, stream>>>(hashProj, cursor, ell);
  hash_gather<<<DIM_B, 1024, 0, stream>>>(x, cursor, ell, out);
}

// Round 4
// 395.857 us; speedup vs baseline: 1.6552x; 1.0001x over previous
//
#include <hip/hip_runtime.h>

// Problem constants (fixed by the reference):
//   x        [B=4096, D=16384] fp32
//   hashProj [D=16384, E=1024] fp32, exactly one nonzero (+-1) per row
//   out      [B=4096, E=1024]  fp32 = x @ hashProj
#define DIM_D 16384
#define DIM_E 1024
#define DIM_B 4096
#define ELL_CAP 64   // bucket capacity; counts ~Poisson(16), P(>64) ~ 1e-50

// ---------------------------------------------------------------------------
// Architecture (ELL gather; LDS-atomic scatter measured 3.25 cyc/lane-op in
// round 2 and is avoided):
//   K1: scan hashProj rows (coalesced float4), founder lane claims a slot in
//       its bucket via atomicAdd(cursor) and writes a ushort entry
//       (j | neg<<15) into the transposed ELL (128 KiB, L2-resident).
//   K2: one 1024-thread block per batch row.
//       - Stage the x row into LDS via 4x width-16 global_load_lds per
//         thread (async DMA, no VGPR round-trip; lane-linear dest).
//       - While the DMA is in flight: read own bucket count, wave-max shuffle
//         for a uniform trip count, prefetch ELL group 0. The serial ~600cyc
//         preamble hides under staging.
//       - __syncthreads() (implicit vmcnt(0) drain) then the gather loop:
//         coalesced 8B ELL loads, 4 independent ds_read chains, entries
//         beyond the bucket's own count masked to +0.0f in VALU (ELL needs
//         no pad prefill -- poisoned garbage decodes in-range, then zeroed).
// Workspace: ell 128 KiB (ushort) + cursor 4 KiB; only cursor is memset.
// ---------------------------------------------------------------------------

__global__ __launch_bounds__(256) void hash_extract_fill(
    const float* __restrict__ hashProj,
    int* __restrict__ cursor,
    unsigned short* __restrict__ ell) {
  const int wave = threadIdx.x >> 6;
  const int lane = threadIdx.x & 63;
  const int row = blockIdx.x * 4 + wave;   // 4096 blocks x 4 waves = 16384 rows
  const float4* rp = (const float4*)(hashProj + (size_t)row * DIM_E);
  int found_e = -1;
  float found_s = 0.f;
#pragma unroll
  for (int k = 0; k < 4; ++k) {
    const int p = lane + 64 * k;           // float4 position within row
    float4 v = rp[p];
    const int base = p * 4;
    if (v.x != 0.f) { found_e = base + 0; found_s = v.x; }
    if (v.y != 0.f) { found_e = base + 1; found_s = v.y; }
    if (v.z != 0.f) { found_e = base + 2; found_s = v.z; }
    if (v.w != 0.f) { found_e = base + 3; found_s = v.w; }
  }
  if (found_e >= 0) {
    const int slot = atomicAdd(&cursor[found_e], 1);   // cursor starts at 0
    if (slot < ELL_CAP) {
      // group g = slot>>2 lives at ushort4 index g*1024+e (lane-consecutive
      // e -> coalesced 8B loads in the gather).
      ell[(slot >> 2) * (4 * DIM_E) + 4 * found_e + (slot & 3)] =
          (unsigned short)(row | ((found_s < 0.f) ? 0x8000 : 0));
    }
  }
}

// Decode entry q (k-th slot of a group whose remaining count is r):
//   valid (k < r): +-xs[j]  (sign bit 15 -> fp32 sign XOR, exact)
//   invalid      : +0.0f    (garbage entries decode in-range, then masked)
__device__ __forceinline__ float ell_val(const float* xs, int q, int k, int r) {
  float v = xs[q & (DIM_D - 1)];
  int iv = __float_as_int(v);
  iv ^= (q & 0x8000) << 16;        // bit15 -> fp32 sign bit
  iv &= (k - r) >> 31;             // k < r ? ~0 : 0
  return __int_as_float(iv);
}

__global__ __launch_bounds__(1024) void hash_gather(
    const float* __restrict__ x,
    const int* __restrict__ cursor,
    const unsigned short* __restrict__ ell,
    float* __restrict__ out) {
  __shared__ float xs[DIM_D];
  const int t = threadIdx.x;
  const int b = blockIdx.x;
  const float* xrow = x + (size_t)b * DIM_D;

  // Async stage: 4 x 16B DMA per thread, lane-linear LDS destination
  // (wave-uniform base + lane*16 -- the global_load_lds constraint).
#pragma unroll
  for (int i = 0; i < 4; ++i) {
    const int p = (t + i * 1024) * 4;      // float index, 16B-aligned
    __builtin_amdgcn_global_load_lds(
        (const __attribute__((address_space(1))) void*)(xrow + p),
        (__attribute__((address_space(3))) void*)(xs + p),
        16, 0, 0);
  }

  // Overlapped with the in-flight DMA: bucket count, wave-uniform trip
  // count, group-0 ELL prefetch.
  int c = cursor[t];
  if (c > ELL_CAP) c = ELL_CAP;
  int m = c;
#pragma unroll
  for (int off = 32; off >= 1; off >>= 1)
    m = max(m, __shfl_xor(m, off));
  const int G = (m + 3) >> 2;              // wave-uniform group count

  const ushort4* ep = (const ushort4*)ell;
  ushort4 q = ep[t];                       // prefetch group 0 (L2-resident)

  __syncthreads();                         // implicit vmcnt(0): DMA complete

  float s0 = 0.f, s1 = 0.f, s2 = 0.f, s3 = 0.f;
  int r = c;
  for (int g = 1; g < G; ++g) {
    ushort4 qn = ep[g * DIM_E + t];        // prefetch next group
    s0 += ell_val(xs, q.x, 0, r);
    s1 += ell_val(xs, q.y, 1, r);
    s2 += ell_val(xs, q.z, 2, r);
    s3 += ell_val(xs, q.w, 3, r);
    q = qn;
    r = c - g * 4;
  }
  s0 += ell_val(xs, q.x, 0, r);
  s1 += ell_val(xs, q.y, 1, r);
  s2 += ell_val(xs, q.z, 2, r);
  s3 += ell_val(xs, q.w, 3, r);
  out[(size_t)b * DIM_E + t] = (s0 + s1) + (s2 + s3);
}

extern "C" void kernel_launch(void* const* d_in, const int* in_sizes, int n_in,
                              void* d_out, int out_size, void* d_ws, size_t ws_size,
                              hipStream_t stream) {
  const float* x = (const float*)d_in[0];
  const float* hashProj = (const float*)d_in[1];
  float* out = (float*)d_out;

  char* ws = (char*)d_ws;
  unsigned short* ell = (unsigned short*)ws;              // 128 KiB
  int* cursor = (int*)(ws + (size_t)ELL_CAP * DIM_E * 2); // 4 KiB

  hipMemsetAsync(cursor, 0, DIM_E * sizeof(int), stream); // only cursors
  hash_extract_fill<<<DIM_D / 4, 256, 0, stream>>>(hashProj, cursor, ell);
  hash_gather<<<DIM_B, 1024, 0, stream>>>(x, cursor, ell, out);
}